// Round 5
// baseline (1045.989 us; speedup 1.0000x reference)
//
#include <hip/hip_runtime.h>
#include <hip/hip_cooperative_groups.h>
#include <math.h>

namespace cg = cooperative_groups;

#define BB 32
#define MM 2048
#define KK 4
#define EE 128
#define GG 128
#define VV 50000
#define NT1 391    // 128-row tiles over V
#define NBLK 1024  // logical (b, slot-chunk) blocks: 32 b x 32 chunks of 64 slots

// ============================================================================
// mega1: GRU + 3 memory hops in ONE cooperative dispatch.
// Phases (grid.sync between): gru -> per hop { t-GEMM, scores+partial-softmax,
// gather(h<2) | attn-out(h==2) }. All phases grid-stride -> correct for any
// grid size >= 32. LDS: 33,280 B union -> 4 blocks/CU, grid 1024 co-resident.
// ============================================================================
__global__ __launch_bounds__(256, 4) void mega1(
    const int*   __restrict__ ctx,    // [B][M][K]
    const int*   __restrict__ y,      // [B]
    const float* __restrict__ hprev,  // [B][G]
    const float* __restrict__ emb,    // [4][V][E]
    const float* __restrict__ W_ih, const float* __restrict__ W_hh,
    const float* __restrict__ b_ih, const float* __restrict__ b_hh,
    float* __restrict__ h_out,        // [B][G]
    float* __restrict__ attn_out,     // [B][M]
    float* __restrict__ q,            // ws [B][E]
    float* __restrict__ o1,           // ws [B][E]
    float* __restrict__ tbuf,         // ws [B][V]
    float* __restrict__ p,            // ws [B][M]
    float* __restrict__ spart)        // ws [B][32][2] = {lmax, lsumexp}
{
    cg::grid_group grid = cg::this_grid();
    __shared__ float shraw[8320];     // 33,280 B union
    // t-phase aliases
    float* Ut = shraw;                // [128][32] idx e*32+b
    float* Wt = shraw + 4096;         // [32][132] idx e*132+v
    // gru aliases
    float* gx  = shraw;               // [128]
    float* ghh = shraw + 128;         // [128]
    float* ggi = shraw + 256;         // [384]
    float* ggh = shraw + 640;         // [384]
    // hop aliases
    float* sp   = shraw;              // [64]
    float* accr = shraw + 64;         // [4][128]

    int bid = blockIdx.x, tid = threadIdx.x, gsz = gridDim.x;

    // ---------------- phase 0: GRU (blocks 0..31) ----------------
    for (int b = bid; b < BB; b += gsz) {
        if (tid < EE)      gx[tid] = emb[(size_t)y[b]*EE + tid];
        else               ghh[tid-EE] = hprev[b*GG + (tid-EE)];
        if (tid < EE)      o1[b*EE + tid] = 0.f;
        __syncthreads();
        for (int r = tid; r < 3*GG; r += 256) {
            float accI = b_ih[r], accH = b_hh[r];
            const float* wi = W_ih + (size_t)r*EE;
            const float* wh = W_hh + (size_t)r*GG;
            #pragma unroll 8
            for (int e = 0; e < EE; e++) { accI += gx[e]*wi[e]; accH += ghh[e]*wh[e]; }
            ggi[r] = accI; ggh[r] = accH;
        }
        __syncthreads();
        if (tid < GG) {
            float r_ = 1.f/(1.f + __expf(-(ggi[tid]      + ggh[tid])));
            float z  = 1.f/(1.f + __expf(-(ggi[GG+tid]   + ggh[GG+tid])));
            float n  = tanhf(ggi[2*GG+tid] + r_*ggh[2*GG+tid]);
            float hn = (1.f - z)*n + z*ghh[tid];
            h_out[b*GG + tid] = hn;
            q[b*GG + tid]     = hn;
        }
        __syncthreads();
    }
    grid.sync();

    // ---------------- hop loop ----------------
    for (int h = 0; h < 3; h++) {
        const float* embA = emb + (size_t)h*VV*EE;

        // --- t-phase: tbuf[b][v] = emb_h[v] . q[b] (dense streaming GEMM) ---
        for (int tile = bid; tile < NT1; tile += gsz) {
            __syncthreads();
            for (int i = tid; i < EE*32; i += 256)
                Ut[i] = q[(size_t)(i & 31)*EE + (i >> 5)];
            int vg = tid & 31, bg = tid >> 5;
            int v0 = tile * 128;
            float acc[4][4];
            #pragma unroll
            for (int i = 0; i < 4; i++)
                #pragma unroll
                for (int j = 0; j < 4; j++) acc[i][j] = 0.f;
            int vrow = tid >> 1, half = tid & 1;
            const float* wrow = embA + (size_t)(v0 + vrow)*EE + half*16;
            bool vok = (v0 + vrow) < VV;
            for (int ec = 0; ec < EE; ec += 32) {
                __syncthreads();
                #pragma unroll
                for (int j = 0; j < 4; j++) {
                    float4 w = make_float4(0.f,0.f,0.f,0.f);
                    if (vok) w = *(const float4*)(wrow + ec + j*4);
                    int e0 = half*16 + j*4;
                    Wt[(e0+0)*132 + vrow] = w.x;
                    Wt[(e0+1)*132 + vrow] = w.y;
                    Wt[(e0+2)*132 + vrow] = w.z;
                    Wt[(e0+3)*132 + vrow] = w.w;
                }
                __syncthreads();
                #pragma unroll 8
                for (int e = 0; e < 32; e++) {
                    float4 w = *(const float4*)(&Wt[e*132 + vg*4]);
                    float4 u = *(const float4*)(&Ut[(ec + e)*32 + bg*4]);
                    acc[0][0] += w.x*u.x; acc[0][1] += w.x*u.y; acc[0][2] += w.x*u.z; acc[0][3] += w.x*u.w;
                    acc[1][0] += w.y*u.x; acc[1][1] += w.y*u.y; acc[1][2] += w.y*u.z; acc[1][3] += w.y*u.w;
                    acc[2][0] += w.z*u.x; acc[2][1] += w.z*u.y; acc[2][2] += w.z*u.z; acc[2][3] += w.z*u.w;
                    acc[3][0] += w.w*u.x; acc[3][1] += w.w*u.y; acc[3][2] += w.w*u.z; acc[3][3] += w.w*u.w;
                }
            }
            #pragma unroll
            for (int i = 0; i < 4; i++) {
                int v = v0 + vg*4 + i;
                if (v < VV) {
                    #pragma unroll
                    for (int j = 0; j < 4; j++)
                        tbuf[(size_t)(bg*4 + j)*VV + v] = acc[i][j];
                }
            }
        }
        grid.sync();

        // --- score phase: p[b][m] = sum_k tbuf[b][ctx]; block-local softmax partials ---
        for (int blk = bid; blk < NBLK; blk += gsz) {
            int b = blk >> 5, s = blk & 31, m0 = s*64;
            int j = tid >> 2, k = tid & 3;
            int m = m0 + j;
            int cidx = ctx[(((size_t)b << 11) + m)*KK + k];
            float val = tbuf[(size_t)b*VV + cidx];
            val += __shfl_down(val, 2);
            val += __shfl_down(val, 1);
            __syncthreads();
            if ((tid & 3) == 0) { sp[j] = val; p[((size_t)b << 11) + m] = val; }
            __syncthreads();
            if (tid < 64) {
                float v1 = sp[tid];
                float m1 = v1;
                #pragma unroll
                for (int off = 32; off; off >>= 1) m1 = fmaxf(m1, __shfl_down(m1, off));
                m1 = __shfl(m1, 0);
                float s1 = __expf(v1 - m1);
                #pragma unroll
                for (int off = 32; off; off >>= 1) s1 += __shfl_down(s1, off);
                if (tid == 0)
                    *(float2*)(spart + ((size_t)b*32 + s)*2) = make_float2(m1, s1);
            }
        }
        grid.sync();

        // --- gather (h<2) or attn output (h==2) ---
        if (h < 2) {
            const float* embC = emb + (size_t)(h+1)*VV*EE;
            for (int blk = bid; blk < NBLK; blk += gsz) {
                int b = blk >> 5, s = blk & 31;
                float M = -INFINITY;
                for (int i2 = 0; i2 < 32; i2++)
                    M = fmaxf(M, spart[((size_t)b*32 + i2)*2]);
                float Z = 0.f;
                for (int i2 = 0; i2 < 32; i2++) {
                    float2 pr = *(const float2*)(spart + ((size_t)b*32 + i2)*2);
                    Z += __expf(pr.x - M) * pr.y;
                }
                float invZ = 1.f / Z;
                int w = tid >> 6, lane = tid & 63;
                int m0 = s*64 + w*16;
                float ax = 0.f, ay = 0.f;
                for (int i = 0; i < 16; i++) {
                    int m = m0 + i;
                    float a = __expf(p[((size_t)b << 11) + m] - M) * invZ;
                    const int4 c = *(const int4*)(ctx + (((size_t)b << 11) + m)*KK);
                    float2 v0 = *(const float2*)(embC + (size_t)c.x*EE + lane*2);
                    float2 v1 = *(const float2*)(embC + (size_t)c.y*EE + lane*2);
                    float2 v2 = *(const float2*)(embC + (size_t)c.z*EE + lane*2);
                    float2 v3 = *(const float2*)(embC + (size_t)c.w*EE + lane*2);
                    ax += a * (v0.x + v1.x + v2.x + v3.x);
                    ay += a * (v0.y + v1.y + v2.y + v3.y);
                }
                __syncthreads();
                accr[w*EE + lane*2]     = ax;
                accr[w*EE + lane*2 + 1] = ay;
                __syncthreads();
                if (tid < EE) {
                    float vv = accr[tid] + accr[EE+tid] + accr[2*EE+tid] + accr[3*EE+tid];
                    atomicAdd(&q[b*EE + tid], vv);
                    if (h == 0) atomicAdd(&o1[b*EE + tid], vv);
                }
            }
        } else {
            for (int blk = bid; blk < NBLK; blk += gsz) {
                int b = blk >> 5, s = blk & 31;
                float M = -INFINITY;
                for (int i2 = 0; i2 < 32; i2++)
                    M = fmaxf(M, spart[((size_t)b*32 + i2)*2]);
                float Z = 0.f;
                for (int i2 = 0; i2 < 32; i2++) {
                    float2 pr = *(const float2*)(spart + ((size_t)b*32 + i2)*2);
                    Z += __expf(pr.x - M) * pr.y;
                }
                float invZ = 1.f / Z;
                if (tid < 64) {
                    int m = s*64 + tid;
                    attn_out[((size_t)b << 11) + m] =
                        __expf(p[((size_t)b << 11) + m] - M) * invZ;
                }
            }
        }
        grid.sync();
    }
}

// ============================================================================
// mega2: vocab logits GEMM + grid.sync + fused vocab softmax (in place).
// LDS 49 KB -> 3 blocks/CU -> up to 768 co-resident >= 391 needed.
// ============================================================================
__global__ __launch_bounds__(256, 3) void mega2(
    const float* __restrict__ h,      // [B][G]
    const float* __restrict__ o1,     // [B][E]
    const float* __restrict__ Wv,     // [V][256]
    const float* __restrict__ bv,     // [V]
    float* __restrict__ logits)       // [B][V] in d_out
{
    cg::grid_group grid = cg::this_grid();
    __shared__ float Ut[256*32];      // [e][b]
    __shared__ float Wt[32*132];      // [e_local][v_local]
    __shared__ float red[8];
    int tid = threadIdx.x, bid = blockIdx.x, gsz = gridDim.x;

    // --- logits GEMM, grid-stride over 128-row tiles ---
    for (int tile = bid; tile < NT1; tile += gsz) {
        __syncthreads();
        for (int i = tid; i < 256*32; i += 256) {
            int e = i >> 5, b = i & 31;
            Ut[i] = (e < GG) ? h[b*GG + e] : o1[b*EE + (e - GG)];
        }
        int vg = tid & 31, bg = tid >> 5;
        int v0 = tile * 128;
        float acc[4][4];
        #pragma unroll
        for (int i = 0; i < 4; i++)
            #pragma unroll
            for (int j = 0; j < 4; j++) acc[i][j] = 0.f;
        int vrow = tid >> 1, half = tid & 1;
        const float* wrow = Wv + (size_t)(v0 + vrow)*256 + half*16;
        bool vok = (v0 + vrow) < VV;
        for (int ec = 0; ec < 256; ec += 32) {
            __syncthreads();
            #pragma unroll
            for (int j = 0; j < 4; j++) {
                float4 w = make_float4(0.f,0.f,0.f,0.f);
                if (vok) w = *(const float4*)(wrow + ec + j*4);
                int e0 = half*16 + j*4;
                Wt[(e0+0)*132 + vrow] = w.x;
                Wt[(e0+1)*132 + vrow] = w.y;
                Wt[(e0+2)*132 + vrow] = w.z;
                Wt[(e0+3)*132 + vrow] = w.w;
            }
            __syncthreads();
            #pragma unroll 8
            for (int e = 0; e < 32; e++) {
                float4 w = *(const float4*)(&Wt[e*132 + vg*4]);
                float4 u = *(const float4*)(&Ut[(ec + e)*32 + bg*4]);
                acc[0][0] += w.x*u.x; acc[0][1] += w.x*u.y; acc[0][2] += w.x*u.z; acc[0][3] += w.x*u.w;
                acc[1][0] += w.y*u.x; acc[1][1] += w.y*u.y; acc[1][2] += w.y*u.z; acc[1][3] += w.y*u.w;
                acc[2][0] += w.z*u.x; acc[2][1] += w.z*u.y; acc[2][2] += w.z*u.z; acc[2][3] += w.z*u.w;
                acc[3][0] += w.w*u.x; acc[3][1] += w.w*u.y; acc[3][2] += w.w*u.z; acc[3][3] += w.w*u.w;
            }
        }
        #pragma unroll
        for (int i = 0; i < 4; i++) {
            int v = v0 + vg*4 + i;
            if (v < VV) {
                float bb = bv[v];
                #pragma unroll
                for (int j = 0; j < 4; j++)
                    logits[(size_t)(bg*4 + j)*VV + v] = acc[i][j] + bb;
            }
        }
    }
    grid.sync();

    // --- fused vocab softmax: blocks 0..31, one full row each (L2-hot) ---
    for (int b = bid; b < BB; b += gsz) {
        float* row = logits + (size_t)b*VV;
        int w = tid >> 6, lane = tid & 63;
        float mx = -INFINITY;
        for (int i = tid; i < VV; i += 256) mx = fmaxf(mx, row[i]);
        #pragma unroll
        for (int off = 32; off; off >>= 1) mx = fmaxf(mx, __shfl_down(mx, off));
        if (lane == 0) red[w] = mx;
        __syncthreads();
        float M = fmaxf(fmaxf(red[0], red[1]), fmaxf(red[2], red[3]));
        float s = 0.f;
        for (int i = tid; i < VV; i += 256) s += __expf(row[i] - M);
        #pragma unroll
        for (int off = 32; off; off >>= 1) s += __shfl_down(s, off);
        __syncthreads();
        if (lane == 0) red[w] = s;
        __syncthreads();
        float invS = 1.f / (red[0] + red[1] + red[2] + red[3]);
        for (int i = tid; i < VV; i += 256) row[i] = __expf(row[i] - M) * invS;
        __syncthreads();
    }
}

extern "C" void kernel_launch(void* const* d_in, const int* in_sizes, int n_in,
                              void* d_out, int out_size, void* d_ws, size_t ws_size,
                              hipStream_t stream) {
    const int*   ctx    = (const int*)  d_in[0];
    const float* h_prev = (const float*)d_in[1];
    const int*   y      = (const int*)  d_in[2];
    const float* emb    = (const float*)d_in[3];
    const float* W_ih   = (const float*)d_in[4];
    const float* W_hh   = (const float*)d_in[5];
    const float* b_ih   = (const float*)d_in[6];
    const float* b_hh   = (const float*)d_in[7];
    const float* Wv     = (const float*)d_in[8];
    const float* bv     = (const float*)d_in[9];

    float* out_h    = (float*)d_out;                 // [B][G]
    float* out_pv   = out_h + BB*GG;                 // [B][V]
    float* out_attn = out_pv + (size_t)BB*VV;        // [B][M]

    float* ws    = (float*)d_ws;
    float* q     = ws;                       // 4096
    float* o1    = q + BB*EE;                // 4096
    float* p     = o1 + BB*EE;               // 65536
    float* tbuf  = p + BB*MM;                // B*V = 1.6M floats
    float* spart = tbuf + (size_t)BB*VV;     // 2048

    // grid sizes: static-safe values (LDS-derived occupancy), refined by query once
    static int g1 = 0, g2 = 0;
    if (g1 == 0) {
        int mb = 0;
        if (hipOccupancyMaxActiveBlocksPerMultiprocessor(
                &mb, reinterpret_cast<const void*>(mega1), 256, 0) == hipSuccess && mb > 0)
            g1 = mb * 256;
        else
            g1 = 4 * 256;                    // LDS 33 KB -> 4 blocks/CU static
        if (g1 > NBLK) g1 = NBLK;
        mb = 0;
        if (hipOccupancyMaxActiveBlocksPerMultiprocessor(
                &mb, reinterpret_cast<const void*>(mega2), 256, 0) == hipSuccess && mb > 0)
            g2 = mb * 256;
        else
            g2 = 3 * 256;                    // LDS 49 KB -> 3 blocks/CU static
        if (g2 > NT1) g2 = NT1;
    }

    void* a1[] = { (void*)&ctx, (void*)&y, (void*)&h_prev, (void*)&emb,
                   (void*)&W_ih, (void*)&W_hh, (void*)&b_ih, (void*)&b_hh,
                   (void*)&out_h, (void*)&out_attn,
                   (void*)&q, (void*)&o1, (void*)&tbuf, (void*)&p, (void*)&spart };
    hipLaunchCooperativeKernel(reinterpret_cast<const void*>(mega1),
                               dim3(g1), dim3(256), a1, 0, stream);

    void* a2[] = { (void*)&out_h, (void*)&o1, (void*)&Wv, (void*)&bv, (void*)&out_pv };
    hipLaunchCooperativeKernel(reinterpret_cast<const void*>(mega2),
                               dim3(g2), dim3(256), a2, 0, stream);
}

// Round 6
// 395.653 us; speedup vs baseline: 2.6437x; 2.6437x over previous
//
#include <hip/hip_runtime.h>
#include <math.h>

#define BB 32
#define MM 2048
#define KK 4
#define EE 128
#define GG 128
#define VV 50000

// ---------------- GRU cell: one block per batch row; also zeroes o1 ----------------
__global__ __launch_bounds__(384) void gru_kernel(
    const float* __restrict__ emb0,   // emb table 0 [V][E]
    const int*   __restrict__ y,      // [B]
    const float* __restrict__ hprev,  // [B][G]
    const float* __restrict__ W_ih,   // [3G][E]
    const float* __restrict__ W_hh,   // [3G][G]
    const float* __restrict__ b_ih,   // [3G]
    const float* __restrict__ b_hh,   // [3G]
    float* __restrict__ h_out,        // d_out [B][G]
    float* __restrict__ q,            // ws    [B][G]
    float* __restrict__ o1)           // ws    [B][E] -> zeroed (atomics later)
{
    int b = blockIdx.x;
    int t = threadIdx.x;
    __shared__ float x[EE], h[GG], gi[3*GG], gh[3*GG];
    if (t < EE)            x[t]       = emb0[(size_t)y[b]*EE + t];
    else if (t < 2*EE)     h[t-EE]    = hprev[b*GG + (t-EE)];
    if (t < EE) o1[b*EE + t] = 0.f;
    __syncthreads();
    {
        float accI = b_ih[t], accH = b_hh[t];
        const float* wi = W_ih + (size_t)t*EE;
        const float* wh = W_hh + (size_t)t*GG;
        #pragma unroll 8
        for (int e = 0; e < EE; e++) { accI += x[e]*wi[e]; accH += h[e]*wh[e]; }
        gi[t] = accI; gh[t] = accH;
    }
    __syncthreads();
    if (t < GG) {
        float r = 1.f/(1.f + __expf(-(gi[t]        + gh[t])));
        float z = 1.f/(1.f + __expf(-(gi[GG+t]     + gh[GG+t])));
        float n = tanhf(gi[2*GG+t] + r*gh[2*GG+t]);
        float hn = (1.f - z)*n + z*h[t];
        h_out[b*GG + t] = hn;
        q[b*GG + t]     = hn;
    }
}

// ---------------- t[b][v] = emb_h[v] . q[b] : dense streaming GEMM ----------------
// 128 v-rows per block, 4v x 4b register tile; table streamed coalesced once.
__global__ __launch_bounds__(256) void t_kernel(
    const float* __restrict__ q,      // [B][E]
    const float* __restrict__ embT,   // [V][E] A-table for this hop
    float* __restrict__ t)            // [B][V]
{
    __shared__ float Ut[EE][32];      // q transposed [e][b]
    __shared__ float Wt[32][132];     // [e_local][v_local], pad 128->132
    int tid = threadIdx.x;
    for (int i = tid; i < EE*32; i += 256) {
        int e = i >> 5, b = i & 31;
        Ut[e][b] = q[b*EE + e];
    }
    int vg = tid & 31;
    int bg = tid >> 5;
    int v0 = blockIdx.x * 128;
    float acc[4][4];
    #pragma unroll
    for (int i = 0; i < 4; i++)
        #pragma unroll
        for (int j = 0; j < 4; j++) acc[i][j] = 0.f;

    int vrow = tid >> 1;
    int half = tid & 1;
    const float* wrow = embT + (size_t)(v0 + vrow)*EE + half*16;
    bool vok = (v0 + vrow) < VV;

    for (int ec = 0; ec < EE; ec += 32) {
        __syncthreads();
        #pragma unroll
        for (int j = 0; j < 4; j++) {
            float4 w = make_float4(0.f, 0.f, 0.f, 0.f);
            if (vok) w = *(const float4*)(wrow + ec + j*4);
            int e0 = half*16 + j*4;
            Wt[e0+0][vrow] = w.x;
            Wt[e0+1][vrow] = w.y;
            Wt[e0+2][vrow] = w.z;
            Wt[e0+3][vrow] = w.w;
        }
        __syncthreads();
        #pragma unroll 8
        for (int e = 0; e < 32; e++) {
            float4 w = *(const float4*)(&Wt[e][vg*4]);
            float4 u = *(const float4*)(&Ut[ec + e][bg*4]);
            acc[0][0] += w.x*u.x; acc[0][1] += w.x*u.y; acc[0][2] += w.x*u.z; acc[0][3] += w.x*u.w;
            acc[1][0] += w.y*u.x; acc[1][1] += w.y*u.y; acc[1][2] += w.y*u.z; acc[1][3] += w.y*u.w;
            acc[2][0] += w.z*u.x; acc[2][1] += w.z*u.y; acc[2][2] += w.z*u.z; acc[2][3] += w.z*u.w;
            acc[3][0] += w.w*u.x; acc[3][1] += w.w*u.y; acc[3][2] += w.w*u.z; acc[3][3] += w.w*u.w;
        }
    }
    #pragma unroll
    for (int i = 0; i < 4; i++) {
        int v = v0 + vg*4 + i;
        if (v < VV) {
            #pragma unroll
            for (int j = 0; j < 4; j++)
                t[(size_t)(bg*4 + j)*VV + v] = acc[i][j];
        }
    }
}

// ---------------- fused: lookup-scores + softmax + gathered weighted read + q update --
// One block per (b, slot-chunk-of-64). Each block recomputes ALL 2048 scores of its
// row from L2-resident tbuf (8192 x 4B lookups) into LDS -- deterministic, identical
// across the 32 blocks of a row -- does softmax locally, then gathers the C-table rows
// for its own 64 slots and atomically accumulates into q (and o1 for hop 0).
// Kills the separate scores dispatch and the global p round-trip.
template<int SAVE_O1>
__global__ __launch_bounds__(256) void oaccL_kernel(
    const float* __restrict__ embC,   // C-table = emb + (hop+1)*V*E
    const int*   __restrict__ ctx,    // [B][M][K]
    const float* __restrict__ tbuf,   // [B][V]
    float* __restrict__ q,            // [B][E] atomic +=
    float* __restrict__ o1)           // [B][E] atomic += (if SAVE_O1)
{
    int blk = blockIdx.x;             // b*32 + s
    int b = blk >> 5, s = blk & 31;
    int tid = threadIdx.x;
    int w = tid >> 6, lane = tid & 63;

    __shared__ float psh[MM];         // 8 KB: the full score row
    __shared__ float red[6];
    __shared__ float accr[4][EE];

    const float* tb = tbuf + (size_t)b*VV;
    const int*   cb = ctx + (size_t)b*MM*KK;

    // --- scores: 8 m per thread, via t-lookups ---
    float v[8];
    float mx = -INFINITY;
    #pragma unroll
    for (int i = 0; i < 8; i++) {
        int m = tid + i*256;
        const int4 c = *(const int4*)(cb + (size_t)m*KK);
        float sc = tb[c.x] + tb[c.y] + tb[c.z] + tb[c.w];
        psh[m] = sc;
        v[i] = sc;
        mx = fmaxf(mx, sc);
    }
    // --- softmax stats (two-level wave reduce, R1-proven pattern) ---
    #pragma unroll
    for (int off = 32; off; off >>= 1) mx = fmaxf(mx, __shfl_down(mx, off));
    if (lane == 0) red[w] = mx;
    __syncthreads();
    if (tid == 0) red[4] = fmaxf(fmaxf(red[0],red[1]), fmaxf(red[2],red[3]));
    __syncthreads();
    mx = red[4];
    float sum = 0.f;
    #pragma unroll
    for (int i = 0; i < 8; i++) sum += __expf(v[i] - mx);
    #pragma unroll
    for (int off = 32; off; off >>= 1) sum += __shfl_down(sum, off);
    __syncthreads();
    if (lane == 0) red[w] = sum;
    __syncthreads();
    if (tid == 0) red[5] = 1.f / (red[0]+red[1]+red[2]+red[3]);
    __syncthreads();
    float rs = red[5];

    // --- gather own 64 slots + weighted accumulate (2-deep MLP unroll) ---
    int m0 = s*64 + w*16;
    float ax = 0.f, ay = 0.f;
    #pragma unroll 2
    for (int i = 0; i < 16; i++) {
        int m = m0 + i;
        float a = __expf(psh[m] - mx) * rs;
        const int4 c = *(const int4*)(cb + (size_t)m*KK);
        float2 v0 = *(const float2*)(embC + (size_t)c.x*EE + lane*2);
        float2 v1 = *(const float2*)(embC + (size_t)c.y*EE + lane*2);
        float2 v2 = *(const float2*)(embC + (size_t)c.z*EE + lane*2);
        float2 v3 = *(const float2*)(embC + (size_t)c.w*EE + lane*2);
        ax += a * (v0.x + v1.x + v2.x + v3.x);
        ay += a * (v0.y + v1.y + v2.y + v3.y);
    }
    __syncthreads();
    accr[w][lane*2]   = ax;
    accr[w][lane*2+1] = ay;
    __syncthreads();
    if (tid < EE) {
        float vv = accr[0][tid] + accr[1][tid] + accr[2][tid] + accr[3][tid];
        atomicAdd(&q[b*EE + tid], vv);
        if (SAVE_O1) atomicAdd(&o1[b*EE + tid], vv);
    }
}

// ---------------- hop 2: fused t-lookup scores + softmax -> attn out ----------------
// One block per batch row, 1024 threads, 2 slots/thread (R4-proven).
__global__ __launch_bounds__(1024) void attn_fused_kernel(
    const float* __restrict__ t,      // [B][V]
    const int*   __restrict__ ctx,    // [B][M][K]
    float* __restrict__ attn_out)     // [B][M]
{
    int b   = blockIdx.x;
    int tid = threadIdx.x;
    const float* tb = t + (size_t)b*VV;
    int m1 = tid, m2 = tid + 1024;
    const int4 c1 = *(const int4*)(ctx + ((size_t)b*MM + m1)*KK);
    const int4 c2 = *(const int4*)(ctx + ((size_t)b*MM + m2)*KK);
    float s1 = tb[c1.x] + tb[c1.y] + tb[c1.z] + tb[c1.w];
    float s2 = tb[c2.x] + tb[c2.y] + tb[c2.z] + tb[c2.w];

    __shared__ float red[16];
    __shared__ float redm, reds;
    int wv = tid >> 6, lane = tid & 63;

    float mx = fmaxf(s1, s2);
    #pragma unroll
    for (int off = 32; off; off >>= 1) mx = fmaxf(mx, __shfl_down(mx, off));
    if (lane == 0) red[wv] = mx;
    __syncthreads();
    if (tid == 0) {
        float m = red[0];
        #pragma unroll
        for (int i = 1; i < 16; i++) m = fmaxf(m, red[i]);
        redm = m;
    }
    __syncthreads();
    mx = redm;
    float e1 = __expf(s1 - mx), e2 = __expf(s2 - mx);
    float sum = e1 + e2;
    #pragma unroll
    for (int off = 32; off; off >>= 1) sum += __shfl_down(sum, off);
    __syncthreads();
    if (lane == 0) red[wv] = sum;
    __syncthreads();
    if (tid == 0) {
        float s = 0.f;
        #pragma unroll
        for (int i = 0; i < 16; i++) s += red[i];
        reds = 1.f / s;
    }
    __syncthreads();
    float rs = reds;
    attn_out[(size_t)b*MM + m1] = e1 * rs;
    attn_out[(size_t)b*MM + m2] = e2 * rs;
}

// ---------------- vocab logits: 50000x32x256 GEMM, 4v x 4b register tile ----------------
__global__ __launch_bounds__(256) void logits_kernel(
    const float* __restrict__ h,      // [B][G]
    const float* __restrict__ o1,     // [B][E]
    const float* __restrict__ Wv,     // [V][256]
    const float* __restrict__ bv,     // [V]
    float* __restrict__ logits)       // [B][V]
{
    __shared__ float Ut[256][32];
    __shared__ float Wt[32][132];
    int t = threadIdx.x;
    for (int i = t; i < 256*32; i += 256) {
        int e = i >> 5, b = i & 31;
        Ut[e][b] = (e < GG) ? h[b*GG + e] : o1[b*EE + (e - GG)];
    }
    int vg = t & 31;
    int bg = t >> 5;
    int v0 = blockIdx.x * 128;
    float acc[4][4];
    #pragma unroll
    for (int i = 0; i < 4; i++)
        #pragma unroll
        for (int j = 0; j < 4; j++) acc[i][j] = 0.f;

    int vrow = t >> 1;
    int half = t & 1;
    const float* wrow = Wv + (size_t)(v0 + vrow)*256 + half*16;
    bool vok = (v0 + vrow) < VV;

    for (int ec = 0; ec < 256; ec += 32) {
        __syncthreads();
        #pragma unroll
        for (int j = 0; j < 4; j++) {
            float4 w = make_float4(0.f, 0.f, 0.f, 0.f);
            if (vok) w = *(const float4*)(wrow + ec + j*4);
            int e0 = half*16 + j*4;
            Wt[e0+0][vrow] = w.x;
            Wt[e0+1][vrow] = w.y;
            Wt[e0+2][vrow] = w.z;
            Wt[e0+3][vrow] = w.w;
        }
        __syncthreads();
        #pragma unroll 8
        for (int e = 0; e < 32; e++) {
            float4 w = *(const float4*)(&Wt[e][vg*4]);
            float4 u = *(const float4*)(&Ut[ec + e][bg*4]);
            acc[0][0] += w.x*u.x; acc[0][1] += w.x*u.y; acc[0][2] += w.x*u.z; acc[0][3] += w.x*u.w;
            acc[1][0] += w.y*u.x; acc[1][1] += w.y*u.y; acc[1][2] += w.y*u.z; acc[1][3] += w.y*u.w;
            acc[2][0] += w.z*u.x; acc[2][1] += w.z*u.y; acc[2][2] += w.z*u.z; acc[2][3] += w.z*u.w;
            acc[3][0] += w.w*u.x; acc[3][1] += w.w*u.y; acc[3][2] += w.w*u.z; acc[3][3] += w.w*u.w;
        }
    }
    #pragma unroll
    for (int i = 0; i < 4; i++) {
        int v = v0 + vg*4 + i;
        if (v < VV) {
            float bb = bv[v];
            #pragma unroll
            for (int j = 0; j < 4; j++)
                logits[(size_t)(bg*4 + j)*VV + v] = acc[i][j] + bb;
        }
    }
}

// ---------------- fused vocab softmax: one block per batch row, in place ----------------
// Row is 200 KB -> L2-hot after the first pass; 3 passes (max, sumexp, normalize).
__global__ __launch_bounds__(1024) void vsm_kernel(
    float* __restrict__ logits)       // [B][V]
{
    int b = blockIdx.x, tid = threadIdx.x;
    float* row = logits + (size_t)b*VV;
    __shared__ float red[16];
    __shared__ float redm, reds;
    int w = tid >> 6, lane = tid & 63;

    float mx = -INFINITY;
    for (int i = tid; i < VV; i += 1024) mx = fmaxf(mx, row[i]);
    #pragma unroll
    for (int off = 32; off; off >>= 1) mx = fmaxf(mx, __shfl_down(mx, off));
    if (lane == 0) red[w] = mx;
    __syncthreads();
    if (tid == 0) {
        float m = red[0];
        #pragma unroll
        for (int i = 1; i < 16; i++) m = fmaxf(m, red[i]);
        redm = m;
    }
    __syncthreads();
    float M = redm;
    float s = 0.f;
    for (int i = tid; i < VV; i += 1024) s += __expf(row[i] - M);
    #pragma unroll
    for (int off = 32; off; off >>= 1) s += __shfl_down(s, off);
    __syncthreads();
    if (lane == 0) red[w] = s;
    __syncthreads();
    if (tid == 0) {
        float z = 0.f;
        #pragma unroll
        for (int i = 0; i < 16; i++) z += red[i];
        reds = 1.f / z;
    }
    __syncthreads();
    float invS = reds;
    for (int i = tid; i < VV; i += 1024) row[i] = __expf(row[i] - M) * invS;
}

extern "C" void kernel_launch(void* const* d_in, const int* in_sizes, int n_in,
                              void* d_out, int out_size, void* d_ws, size_t ws_size,
                              hipStream_t stream) {
    const int*   ctx    = (const int*)  d_in[0];
    const float* h_prev = (const float*)d_in[1];
    const int*   y      = (const int*)  d_in[2];
    const float* emb    = (const float*)d_in[3];
    const float* W_ih   = (const float*)d_in[4];
    const float* W_hh   = (const float*)d_in[5];
    const float* b_ih   = (const float*)d_in[6];
    const float* b_hh   = (const float*)d_in[7];
    const float* Wv     = (const float*)d_in[8];
    const float* bv     = (const float*)d_in[9];

    float* out_h    = (float*)d_out;                 // [B][G]
    float* out_pv   = out_h + BB*GG;                 // [B][V]
    float* out_attn = out_pv + (size_t)BB*VV;        // [B][M]

    float* ws   = (float*)d_ws;
    float* q    = ws;                       // 4096
    float* o1   = q + BB*EE;                // 4096
    float* tbuf = o1 + BB*EE;               // B*V = 1.6M floats (6.4 MB)

    const float* e0 = emb;
    const float* e1 = emb + (size_t)1*VV*EE;
    const float* e2 = emb + (size_t)2*VV*EE;

    // GRU -> h, q ; zero o1
    gru_kernel<<<BB, 384, 0, stream>>>(emb, y, h_prev, W_ih, W_hh, b_ih, b_hh, out_h, q, o1);

    // hop 0: t0 stream-GEMM; fused lookup-scores+softmax+gather; q += o0, o1 = o0
    t_kernel<<<391, 256, 0, stream>>>(q, e0, tbuf);
    oaccL_kernel<1><<<BB*32, 256, 0, stream>>>(e1, ctx, tbuf, q, o1);

    // hop 1
    t_kernel<<<391, 256, 0, stream>>>(q, e1, tbuf);
    oaccL_kernel<0><<<BB*32, 256, 0, stream>>>(e2, ctx, tbuf, q, nullptr);

    // hop 2: only attn = softmax(scores) observable (o/q dead in reference)
    t_kernel<<<391, 256, 0, stream>>>(q, e2, tbuf);
    attn_fused_kernel<<<BB, 1024, 0, stream>>>(tbuf, ctx, out_attn);

    // vocab head: logits GEMM + fused single-dispatch softmax
    logits_kernel<<<391, 256, 0, stream>>>(out_h, o1, Wv, bv, out_pv);
    vsm_kernel<<<BB, 1024, 0, stream>>>(out_pv);
}

// Round 7
// 384.393 us; speedup vs baseline: 2.7211x; 1.0293x over previous
//
#include <hip/hip_runtime.h>
#include <math.h>

#define BB 32
#define MM 2048
#define KK 4
#define EE 128
#define GG 128
#define VV 50000

// ---------------- GRU cell: one block per batch row; also zeroes o1 ----------------
__global__ __launch_bounds__(384) void gru_kernel(
    const float* __restrict__ emb0,   // emb table 0 [V][E]
    const int*   __restrict__ y,      // [B]
    const float* __restrict__ hprev,  // [B][G]
    const float* __restrict__ W_ih,   // [3G][E]
    const float* __restrict__ W_hh,   // [3G][G]
    const float* __restrict__ b_ih,   // [3G]
    const float* __restrict__ b_hh,   // [3G]
    float* __restrict__ h_out,        // d_out [B][G]
    float* __restrict__ q,            // ws    [B][G]
    float* __restrict__ o1)           // ws    [B][E] -> zeroed (atomics later)
{
    int b = blockIdx.x;
    int t = threadIdx.x;
    __shared__ float x[EE], h[GG], gi[3*GG], gh[3*GG];
    if (t < EE)            x[t]       = emb0[(size_t)y[b]*EE + t];
    else if (t < 2*EE)     h[t-EE]    = hprev[b*GG + (t-EE)];
    if (t < EE) o1[b*EE + t] = 0.f;
    __syncthreads();
    {
        float accI = b_ih[t], accH = b_hh[t];
        const float* wi = W_ih + (size_t)t*EE;
        const float* wh = W_hh + (size_t)t*GG;
        #pragma unroll 8
        for (int e = 0; e < EE; e++) { accI += x[e]*wi[e]; accH += h[e]*wh[e]; }
        gi[t] = accI; gh[t] = accH;
    }
    __syncthreads();
    if (t < GG) {
        float r = 1.f/(1.f + __expf(-(gi[t]        + gh[t])));
        float z = 1.f/(1.f + __expf(-(gi[GG+t]     + gh[GG+t])));
        float n = tanhf(gi[2*GG+t] + r*gh[2*GG+t]);
        float hn = (1.f - z)*n + z*h[t];
        h_out[b*GG + t] = hn;
        q[b*GG + t]     = hn;
    }
}

// ---------------- t[b][v] = emb0[v] . q[b] : dense streaming GEMM (hop 0 scores) ----
__global__ __launch_bounds__(256) void t_kernel(
    const float* __restrict__ q,      // [B][E]
    const float* __restrict__ embT,   // [V][E]
    float* __restrict__ t)            // [B][V]
{
    __shared__ float Ut[EE][32];      // q transposed [e][b]
    __shared__ float Wt[32][132];     // [e_local][v_local], pad 128->132
    int tid = threadIdx.x;
    for (int i = tid; i < EE*32; i += 256) {
        int e = i >> 5, b = i & 31;
        Ut[e][b] = q[b*EE + e];
    }
    int vg = tid & 31;
    int bg = tid >> 5;
    int v0 = blockIdx.x * 128;
    float acc[4][4];
    #pragma unroll
    for (int i = 0; i < 4; i++)
        #pragma unroll
        for (int j = 0; j < 4; j++) acc[i][j] = 0.f;

    int vrow = tid >> 1;
    int half = tid & 1;
    const float* wrow = embT + (size_t)(v0 + vrow)*EE + half*16;
    bool vok = (v0 + vrow) < VV;

    for (int ec = 0; ec < EE; ec += 32) {
        __syncthreads();
        #pragma unroll
        for (int j = 0; j < 4; j++) {
            float4 w = make_float4(0.f, 0.f, 0.f, 0.f);
            if (vok) w = *(const float4*)(wrow + ec + j*4);
            int e0 = half*16 + j*4;
            Wt[e0+0][vrow] = w.x;
            Wt[e0+1][vrow] = w.y;
            Wt[e0+2][vrow] = w.z;
            Wt[e0+3][vrow] = w.w;
        }
        __syncthreads();
        #pragma unroll 8
        for (int e = 0; e < 32; e++) {
            float4 w = *(const float4*)(&Wt[e][vg*4]);
            float4 u = *(const float4*)(&Ut[ec + e][bg*4]);
            acc[0][0] += w.x*u.x; acc[0][1] += w.x*u.y; acc[0][2] += w.x*u.z; acc[0][3] += w.x*u.w;
            acc[1][0] += w.y*u.x; acc[1][1] += w.y*u.y; acc[1][2] += w.y*u.z; acc[1][3] += w.y*u.w;
            acc[2][0] += w.z*u.x; acc[2][1] += w.z*u.y; acc[2][2] += w.z*u.z; acc[2][3] += w.z*u.w;
            acc[3][0] += w.w*u.x; acc[3][1] += w.w*u.y; acc[3][2] += w.w*u.z; acc[3][3] += w.w*u.w;
        }
    }
    #pragma unroll
    for (int i = 0; i < 4; i++) {
        int v = v0 + vg*4 + i;
        if (v < VV) {
            #pragma unroll
            for (int j = 0; j < 4; j++)
                t[(size_t)(bg*4 + j)*VV + v] = acc[i][j];
        }
    }
}

// ---------------- hop 0 scores via t-lookup: p[b][m] = sum_k t[b][ctx] ----------------
__global__ __launch_bounds__(256) void scores_lookup_kernel(
    const float* __restrict__ t,      // [B][V]
    const int*   __restrict__ ctx,    // [B][M][K]
    float* __restrict__ p)            // [B][M]
{
    int gid = blockIdx.x*256 + threadIdx.x;   // == b*M + m
    int b   = gid >> 11;
    const int4 c = *(const int4*)(ctx + (size_t)gid*KK);
    const float* tb = t + (size_t)b*VV;
    p[gid] = tb[c.x] + tb[c.y] + tb[c.z] + tb[c.w];
}

// ---------------- fused: softmax stats + gathered weighted read + S write + q update --
// R1-proven. One block per (b, slot-chunk-of-64). Recomputes row softmax stats from p
// (8 KB read), gathers C-table rows, writes S row-sums (weight tying: C of hop h ==
// A of hop h+1, reused for next hop's streamed scores), atomic-accumulates into q/o1.
template<int SAVE_O1>
__global__ __launch_bounds__(256) void oacc_fused_kernel(
    const float* __restrict__ embT,   // emb + (hop+1)*V*E
    const int*   __restrict__ ctx,    // [B][M][K]
    const float* __restrict__ p,      // [B][M] raw scores
    float* __restrict__ S_out,        // [B*M][E] row sums
    float* __restrict__ q,            // [B][E] atomic +=
    float* __restrict__ o1)           // [B][E] atomic += (if SAVE_O1)
{
    int blk = blockIdx.x;             // b*32 + s
    int b = blk >> 5, s = blk & 31;
    int t = threadIdx.x;
    int w = t >> 6, lane = t & 63;

    const float* row = p + (size_t)b*MM;
    float v[8];
    float mx = -INFINITY;
    #pragma unroll
    for (int i = 0; i < 8; i++) { v[i] = row[t + i*256]; mx = fmaxf(mx, v[i]); }
    __shared__ float red[6];
    #pragma unroll
    for (int off = 32; off; off >>= 1) mx = fmaxf(mx, __shfl_down(mx, off));
    if (lane == 0) red[w] = mx;
    __syncthreads();
    if (t == 0) red[4] = fmaxf(fmaxf(red[0],red[1]), fmaxf(red[2],red[3]));
    __syncthreads();
    mx = red[4];
    float sum = 0.f;
    #pragma unroll
    for (int i = 0; i < 8; i++) sum += __expf(v[i] - mx);
    #pragma unroll
    for (int off = 32; off; off >>= 1) sum += __shfl_down(sum, off);
    __syncthreads();
    if (lane == 0) red[w] = sum;
    __syncthreads();
    if (t == 0) red[5] = 1.f / (red[0]+red[1]+red[2]+red[3]);
    __syncthreads();
    float rs = red[5];

    int m0 = s*64 + w*16;
    float ax = 0.f, ay = 0.f;
    #pragma unroll 2
    for (int i = 0; i < 16; i++) {
        int m = m0 + i;
        float a = __expf(row[m] - mx) * rs;
        const int4 c = *(const int4*)(ctx + (size_t)(b*MM + m)*KK);
        float2 v0 = *(const float2*)(embT + (size_t)c.x*EE + lane*2);
        float2 v1 = *(const float2*)(embT + (size_t)c.y*EE + lane*2);
        float2 v2 = *(const float2*)(embT + (size_t)c.z*EE + lane*2);
        float2 v3 = *(const float2*)(embT + (size_t)c.w*EE + lane*2);
        float sx = v0.x + v1.x + v2.x + v3.x;
        float sy = v0.y + v1.y + v2.y + v3.y;
        *(float2*)(S_out + ((size_t)b*MM + m)*EE + lane*2) = make_float2(sx, sy);
        ax += a * sx;
        ay += a * sy;
    }
    __shared__ float acc_red[4][EE];
    acc_red[w][lane*2]   = ax;
    acc_red[w][lane*2+1] = ay;
    __syncthreads();
    if (t < EE) {
        float vv = acc_red[0][t] + acc_red[1][t] + acc_red[2][t] + acc_red[3][t];
        atomicAdd(&q[b*EE + t], vv);
        if (SAVE_O1) atomicAdd(&o1[b*EE + t], vv);
    }
}

// ---------------- streamed scores from S (hop 1): p[b][m] = S[b][m].q[b] ----------------
__global__ __launch_bounds__(256) void scores_s_kernel(
    const float* __restrict__ S,      // [B*M][E]
    const float* __restrict__ q,      // [B][E]
    float* __restrict__ p)            // [B][M]
{
    int gid  = blockIdx.x * 4 + (threadIdx.x >> 6);
    int lane = threadIdx.x & 63;
    int b    = gid >> 11;
    float2 sv = *(const float2*)(S + (size_t)gid*EE + lane*2);
    float2 qv = *(const float2*)(q + b*EE + lane*2);
    float acc = sv.x*qv.x + sv.y*qv.y;
    #pragma unroll
    for (int off = 32; off; off >>= 1) acc += __shfl_down(acc, off);
    if (lane == 0) p[gid] = acc;
}

// ---------------- hop 2 fused: streamed scores from S2 + softmax -> attn out ----------
// One block per batch row, 1024 threads (16 waves). Each wave computes 128 slot scores
// (wave-wide dot over the streamed S row) into LDS, then block softmax, write attn.
__global__ __launch_bounds__(1024) void attn_s_kernel(
    const float* __restrict__ S,      // [B*M][E]
    const float* __restrict__ q,      // [B][E]
    float* __restrict__ attn_out)     // [B][M]
{
    int b   = blockIdx.x;
    int tid = threadIdx.x;
    int wv = tid >> 6, lane = tid & 63;
    __shared__ float psh[MM];         // 8 KB
    __shared__ float red[16];
    __shared__ float redm, reds;

    float2 qv = *(const float2*)(q + b*EE + lane*2);
    for (int i = 0; i < 128; i++) {
        int m = wv*128 + i;
        float2 sv = *(const float2*)(S + ((size_t)b*MM + m)*EE + lane*2);
        float acc = sv.x*qv.x + sv.y*qv.y;
        #pragma unroll
        for (int off = 32; off; off >>= 1) acc += __shfl_down(acc, off);
        if (lane == 0) psh[m] = acc;
    }
    __syncthreads();

    float s1 = psh[tid], s2 = psh[tid + 1024];
    float mx = fmaxf(s1, s2);
    #pragma unroll
    for (int off = 32; off; off >>= 1) mx = fmaxf(mx, __shfl_down(mx, off));
    if (lane == 0) red[wv] = mx;
    __syncthreads();
    if (tid == 0) {
        float m = red[0];
        #pragma unroll
        for (int i = 1; i < 16; i++) m = fmaxf(m, red[i]);
        redm = m;
    }
    __syncthreads();
    mx = redm;
    float e1 = __expf(s1 - mx), e2 = __expf(s2 - mx);
    float sum = e1 + e2;
    #pragma unroll
    for (int off = 32; off; off >>= 1) sum += __shfl_down(sum, off);
    __syncthreads();
    if (lane == 0) red[wv] = sum;
    __syncthreads();
    if (tid == 0) {
        float z = 0.f;
        #pragma unroll
        for (int i = 0; i < 16; i++) z += red[i];
        reds = 1.f / z;
    }
    __syncthreads();
    float rs = reds;
    attn_out[(size_t)b*MM + tid]        = e1 * rs;
    attn_out[(size_t)b*MM + tid + 1024] = e2 * rs;
}

// ---------------- vocab logits: 50000x32x256 GEMM, 4v x 4b register tile ----------------
__global__ __launch_bounds__(256) void logits_kernel(
    const float* __restrict__ h,      // [B][G]
    const float* __restrict__ o1,     // [B][E]
    const float* __restrict__ Wv,     // [V][256]
    const float* __restrict__ bv,     // [V]
    float* __restrict__ logits)       // [B][V]
{
    __shared__ float Ut[256][32];
    __shared__ float Wt[32][132];
    int t = threadIdx.x;
    for (int i = t; i < 256*32; i += 256) {
        int e = i >> 5, b = i & 31;
        Ut[e][b] = (e < GG) ? h[b*GG + e] : o1[b*EE + (e - GG)];
    }
    int vg = t & 31;
    int bg = t >> 5;
    int v0 = blockIdx.x * 128;
    float acc[4][4];
    #pragma unroll
    for (int i = 0; i < 4; i++)
        #pragma unroll
        for (int j = 0; j < 4; j++) acc[i][j] = 0.f;

    int vrow = t >> 1;
    int half = t & 1;
    const float* wrow = Wv + (size_t)(v0 + vrow)*256 + half*16;
    bool vok = (v0 + vrow) < VV;

    for (int ec = 0; ec < 256; ec += 32) {
        __syncthreads();
        #pragma unroll
        for (int j = 0; j < 4; j++) {
            float4 w = make_float4(0.f, 0.f, 0.f, 0.f);
            if (vok) w = *(const float4*)(wrow + ec + j*4);
            int e0 = half*16 + j*4;
            Wt[e0+0][vrow] = w.x;
            Wt[e0+1][vrow] = w.y;
            Wt[e0+2][vrow] = w.z;
            Wt[e0+3][vrow] = w.w;
        }
        __syncthreads();
        #pragma unroll 8
        for (int e = 0; e < 32; e++) {
            float4 w = *(const float4*)(&Wt[e][vg*4]);
            float4 u = *(const float4*)(&Ut[ec + e][bg*4]);
            acc[0][0] += w.x*u.x; acc[0][1] += w.x*u.y; acc[0][2] += w.x*u.z; acc[0][3] += w.x*u.w;
            acc[1][0] += w.y*u.x; acc[1][1] += w.y*u.y; acc[1][2] += w.y*u.z; acc[1][3] += w.y*u.w;
            acc[2][0] += w.z*u.x; acc[2][1] += w.z*u.y; acc[2][2] += w.z*u.z; acc[2][3] += w.z*u.w;
            acc[3][0] += w.w*u.x; acc[3][1] += w.w*u.y; acc[3][2] += w.w*u.z; acc[3][3] += w.w*u.w;
        }
    }
    #pragma unroll
    for (int i = 0; i < 4; i++) {
        int v = v0 + vg*4 + i;
        if (v < VV) {
            float bb = bv[v];
            #pragma unroll
            for (int j = 0; j < 4; j++)
                logits[(size_t)(bg*4 + j)*VV + v] = acc[i][j] + bb;
        }
    }
}

// ---------------- fused vocab softmax: one block per batch row, in place ----------------
__global__ __launch_bounds__(1024) void vsm_kernel(
    float* __restrict__ logits)       // [B][V]
{
    int b = blockIdx.x, tid = threadIdx.x;
    float* row = logits + (size_t)b*VV;
    __shared__ float red[16];
    __shared__ float redm, reds;
    int w = tid >> 6, lane = tid & 63;

    float mx = -INFINITY;
    for (int i = tid; i < VV; i += 1024) mx = fmaxf(mx, row[i]);
    #pragma unroll
    for (int off = 32; off; off >>= 1) mx = fmaxf(mx, __shfl_down(mx, off));
    if (lane == 0) red[w] = mx;
    __syncthreads();
    if (tid == 0) {
        float m = red[0];
        #pragma unroll
        for (int i = 1; i < 16; i++) m = fmaxf(m, red[i]);
        redm = m;
    }
    __syncthreads();
    float M = redm;
    float s = 0.f;
    for (int i = tid; i < VV; i += 1024) s += __expf(row[i] - M);
    #pragma unroll
    for (int off = 32; off; off >>= 1) s += __shfl_down(s, off);
    __syncthreads();
    if (lane == 0) red[w] = s;
    __syncthreads();
    if (tid == 0) {
        float z = 0.f;
        #pragma unroll
        for (int i = 0; i < 16; i++) z += red[i];
        reds = 1.f / z;
    }
    __syncthreads();
    float invS = reds;
    for (int i = tid; i < VV; i += 1024) row[i] = __expf(row[i] - M) * invS;
}

extern "C" void kernel_launch(void* const* d_in, const int* in_sizes, int n_in,
                              void* d_out, int out_size, void* d_ws, size_t ws_size,
                              hipStream_t stream) {
    const int*   ctx    = (const int*)  d_in[0];
    const float* h_prev = (const float*)d_in[1];
    const int*   y      = (const int*)  d_in[2];
    const float* emb    = (const float*)d_in[3];
    const float* W_ih   = (const float*)d_in[4];
    const float* W_hh   = (const float*)d_in[5];
    const float* b_ih   = (const float*)d_in[6];
    const float* b_hh   = (const float*)d_in[7];
    const float* Wv     = (const float*)d_in[8];
    const float* bv     = (const float*)d_in[9];

    float* out_h    = (float*)d_out;                 // [B][G]
    float* out_pv   = out_h + BB*GG;                 // [B][V]
    float* out_attn = out_pv + (size_t)BB*VV;        // [B][M]

    float* ws   = (float*)d_ws;
    float* q    = ws;                       // 4096
    float* o1   = q + BB*EE;                // 4096
    float* p    = o1 + BB*EE;               // 65536
    float* tbuf = p + BB*MM;                // B*V (6.4 MB)
    float* S1   = tbuf + (size_t)BB*VV;     // 33.5 MB
    float* S2   = S1 + (size_t)BB*MM*EE;    // 33.5 MB

    const float* e0 = emb;
    const float* e1 = emb + (size_t)1*VV*EE;
    const float* e2 = emb + (size_t)2*VV*EE;

    // GRU -> h, q ; zero o1
    gru_kernel<<<BB, 384, 0, stream>>>(emb, y, h_prev, W_ih, W_hh, b_ih, b_hh, out_h, q, o1);

    // hop 0: scores via table-0 stream + L2 lookup (t-trick); gather table1 + write S1
    t_kernel<<<391, 256, 0, stream>>>(q, e0, tbuf);
    scores_lookup_kernel<<<(BB*MM)/256, 256, 0, stream>>>(tbuf, ctx, p);
    oacc_fused_kernel<1><<<BB*32, 256, 0, stream>>>(e1, ctx, p, S1, q, o1);

    // hop 1: streamed scores from S1; gather table2 + write S2
    scores_s_kernel<<<(BB*MM)/4, 256, 0, stream>>>(S1, q, p);
    oacc_fused_kernel<0><<<BB*32, 256, 0, stream>>>(e2, ctx, p, S2, q, nullptr);

    // hop 2: fused streamed scores from S2 + softmax -> attn (o/q dead in reference)
    attn_s_kernel<<<BB, 1024, 0, stream>>>(S2, q, out_attn);

    // vocab head
    logits_kernel<<<391, 256, 0, stream>>>(out_h, o1, Wv, bv, out_pv);
    vsm_kernel<<<BB, 1024, 0, stream>>>(out_pv);
}

// Round 8
// 320.371 us; speedup vs baseline: 3.2649x; 1.1998x over previous
//
#include <hip/hip_runtime.h>
#include <math.h>

#define BB 32
#define MM 2048
#define KK 4
#define EE 128
#define GG 128
#define VV 50000

// ---------------- GRU cell: one block per batch row; also zeroes o1 ----------------
__global__ __launch_bounds__(384) void gru_kernel(
    const float* __restrict__ emb0,   // emb table 0 [V][E]
    const int*   __restrict__ y,      // [B]
    const float* __restrict__ hprev,  // [B][G]
    const float* __restrict__ W_ih,   // [3G][E]
    const float* __restrict__ W_hh,   // [3G][G]
    const float* __restrict__ b_ih,   // [3G]
    const float* __restrict__ b_hh,   // [3G]
    float* __restrict__ h_out,        // d_out [B][G]
    float* __restrict__ q,            // ws    [B][G]
    float* __restrict__ o1)           // ws    [B][E] -> zeroed (atomics later)
{
    int b = blockIdx.x;
    int t = threadIdx.x;
    __shared__ float x[EE], h[GG], gi[3*GG], gh[3*GG];
    if (t < EE)            x[t]       = emb0[(size_t)y[b]*EE + t];
    else if (t < 2*EE)     h[t-EE]    = hprev[b*GG + (t-EE)];
    if (t < EE) o1[b*EE + t] = 0.f;
    __syncthreads();
    {
        float accI = b_ih[t], accH = b_hh[t];
        const float* wi = W_ih + (size_t)t*EE;
        const float* wh = W_hh + (size_t)t*GG;
        #pragma unroll 8
        for (int e = 0; e < EE; e++) { accI += x[e]*wi[e]; accH += h[e]*wh[e]; }
        gi[t] = accI; gh[t] = accH;
    }
    __syncthreads();
    if (t < GG) {
        float r = 1.f/(1.f + __expf(-(gi[t]        + gh[t])));
        float z = 1.f/(1.f + __expf(-(gi[GG+t]     + gh[GG+t])));
        float n = tanhf(gi[2*GG+t] + r*gh[2*GG+t]);
        float hn = (1.f - z)*n + z*h[t];
        h_out[b*GG + t] = hn;
        q[b*GG + t]     = hn;
    }
}

// ---------------- t[b][v] = emb0[v] . q[b] : dense streaming GEMM (hop 0 scores) ----
// Replaces the 128 MB semi-random gather (measured ~3.5 TB/s effective) with a
// 25.6 MB coalesced table stream + 6.4 MB write.
__global__ __launch_bounds__(256) void t_kernel(
    const float* __restrict__ q,      // [B][E]
    const float* __restrict__ embT,   // [V][E]
    float* __restrict__ t)            // [B][V]
{
    __shared__ float Ut[EE][32];      // q transposed [e][b]
    __shared__ float Wt[32][132];     // [e_local][v_local], pad 128->132
    int tid = threadIdx.x;
    for (int i = tid; i < EE*32; i += 256) {
        int e = i >> 5, b = i & 31;
        Ut[e][b] = q[b*EE + e];
    }
    int vg = tid & 31;
    int bg = tid >> 5;
    int v0 = blockIdx.x * 128;
    float acc[4][4];
    #pragma unroll
    for (int i = 0; i < 4; i++)
        #pragma unroll
        for (int j = 0; j < 4; j++) acc[i][j] = 0.f;

    int vrow = tid >> 1;
    int half = tid & 1;
    const float* wrow = embT + (size_t)(v0 + vrow)*EE + half*16;
    bool vok = (v0 + vrow) < VV;

    for (int ec = 0; ec < EE; ec += 32) {
        __syncthreads();
        #pragma unroll
        for (int j = 0; j < 4; j++) {
            float4 w = make_float4(0.f, 0.f, 0.f, 0.f);
            if (vok) w = *(const float4*)(wrow + ec + j*4);
            int e0 = half*16 + j*4;
            Wt[e0+0][vrow] = w.x;
            Wt[e0+1][vrow] = w.y;
            Wt[e0+2][vrow] = w.z;
            Wt[e0+3][vrow] = w.w;
        }
        __syncthreads();
        #pragma unroll 8
        for (int e = 0; e < 32; e++) {
            float4 w = *(const float4*)(&Wt[e][vg*4]);
            float4 u = *(const float4*)(&Ut[ec + e][bg*4]);
            acc[0][0] += w.x*u.x; acc[0][1] += w.x*u.y; acc[0][2] += w.x*u.z; acc[0][3] += w.x*u.w;
            acc[1][0] += w.y*u.x; acc[1][1] += w.y*u.y; acc[1][2] += w.y*u.z; acc[1][3] += w.y*u.w;
            acc[2][0] += w.z*u.x; acc[2][1] += w.z*u.y; acc[2][2] += w.z*u.z; acc[2][3] += w.z*u.w;
            acc[3][0] += w.w*u.x; acc[3][1] += w.w*u.y; acc[3][2] += w.w*u.z; acc[3][3] += w.w*u.w;
        }
    }
    #pragma unroll
    for (int i = 0; i < 4; i++) {
        int v = v0 + vg*4 + i;
        if (v < VV) {
            #pragma unroll
            for (int j = 0; j < 4; j++)
                t[(size_t)(bg*4 + j)*VV + v] = acc[i][j];
        }
    }
}

// ---------------- hop 0 scores via t-lookup: p[b][m] = sum_k t[b][ctx] ----------------
__global__ __launch_bounds__(256) void scores_lookup_kernel(
    const float* __restrict__ t,      // [B][V]
    const int*   __restrict__ ctx,    // [B][M][K]
    float* __restrict__ p)            // [B][M]
{
    int gid = blockIdx.x*256 + threadIdx.x;   // == b*M + m
    int b   = gid >> 11;
    const int4 c = *(const int4*)(ctx + (size_t)gid*KK);
    const float* tb = t + (size_t)b*VV;
    p[gid] = tb[c.x] + tb[c.y] + tb[c.z] + tb[c.w];
}

// ---------------- fused: softmax stats + weighted gather + S write + q update ----------
// R1-proven. One block per (b, slot-chunk-of-64). Recomputes row softmax stats from p
// (8 KB read), gathers the C-table rows, writes S row-sums (weight tying: C of hop h
// == A of hop h+1 -> next hop's streamed scores), atomically accumulates into q (/o1).
template<int SAVE_O1>
__global__ __launch_bounds__(256) void oacc_fused_kernel(
    const float* __restrict__ embT,   // emb + (hop+1)*V*E
    const int*   __restrict__ ctx,    // [B][M][K]
    const float* __restrict__ p,      // [B][M] raw scores
    float* __restrict__ S_out,        // [B*M][E] row sums
    float* __restrict__ q,            // [B][E] atomic +=
    float* __restrict__ o1)           // [B][E] atomic += (if SAVE_O1)
{
    int blk = blockIdx.x;             // b*32 + s
    int b = blk >> 5, s = blk & 31;
    int t = threadIdx.x;
    int w = t >> 6, lane = t & 63;

    const float* row = p + (size_t)b*MM;
    float v[8];
    float mx = -INFINITY;
    #pragma unroll
    for (int i = 0; i < 8; i++) { v[i] = row[t + i*256]; mx = fmaxf(mx, v[i]); }
    __shared__ float red[6];
    #pragma unroll
    for (int off = 32; off; off >>= 1) mx = fmaxf(mx, __shfl_down(mx, off));
    if (lane == 0) red[w] = mx;
    __syncthreads();
    if (t == 0) red[4] = fmaxf(fmaxf(red[0],red[1]), fmaxf(red[2],red[3]));
    __syncthreads();
    mx = red[4];
    float sum = 0.f;
    #pragma unroll
    for (int i = 0; i < 8; i++) sum += __expf(v[i] - mx);
    #pragma unroll
    for (int off = 32; off; off >>= 1) sum += __shfl_down(sum, off);
    __syncthreads();
    if (lane == 0) red[w] = sum;
    __syncthreads();
    if (t == 0) red[5] = 1.f / (red[0]+red[1]+red[2]+red[3]);
    __syncthreads();
    float rs = red[5];

    int m0 = s*64 + w*16;
    float ax = 0.f, ay = 0.f;
    for (int i = 0; i < 16; i++) {
        int m = m0 + i;
        float a = __expf(row[m] - mx) * rs;
        const int4 c = *(const int4*)(ctx + (size_t)(b*MM + m)*KK);
        float2 v0 = *(const float2*)(embT + (size_t)c.x*EE + lane*2);
        float2 v1 = *(const float2*)(embT + (size_t)c.y*EE + lane*2);
        float2 v2 = *(const float2*)(embT + (size_t)c.z*EE + lane*2);
        float2 v3 = *(const float2*)(embT + (size_t)c.w*EE + lane*2);
        float sx = v0.x + v1.x + v2.x + v3.x;
        float sy = v0.y + v1.y + v2.y + v3.y;
        *(float2*)(S_out + ((size_t)b*MM + m)*EE + lane*2) = make_float2(sx, sy);
        ax += a * sx;
        ay += a * sy;
    }
    __shared__ float acc_red[4][EE];
    acc_red[w][lane*2]   = ax;
    acc_red[w][lane*2+1] = ay;
    __syncthreads();
    if (t < EE) {
        float vv = acc_red[0][t] + acc_red[1][t] + acc_red[2][t] + acc_red[3][t];
        atomicAdd(&q[b*EE + t], vv);
        if (SAVE_O1) atomicAdd(&o1[b*EE + t], vv);
    }
}

// ---------------- streamed scores from S: p[b][m] = S[b][m].q[b] ----------------
__global__ __launch_bounds__(256) void scores_s_kernel(
    const float* __restrict__ S,      // [B*M][E]
    const float* __restrict__ q,      // [B][E]
    float* __restrict__ p)            // [B][M]
{
    int gid  = blockIdx.x * 4 + (threadIdx.x >> 6);
    int lane = threadIdx.x & 63;
    int b    = gid >> 11;
    float2 sv = *(const float2*)(S + (size_t)gid*EE + lane*2);
    float2 qv = *(const float2*)(q + b*EE + lane*2);
    float acc = sv.x*qv.x + sv.y*qv.y;
    #pragma unroll
    for (int off = 32; off; off >>= 1) acc += __shfl_down(acc, off);
    if (lane == 0) p[gid] = acc;
}

// ---------------- softmax over M: writes final attn output (hop 2) ----------------
__global__ __launch_bounds__(256) void softmax_m_kernel(
    const float* __restrict__ p,      // [B][M]
    float* __restrict__ attn)         // [B][M]
{
    int b = blockIdx.x, t = threadIdx.x;
    const float* row = p + (size_t)b*MM;
    float v[8];
    float mx = -INFINITY;
    #pragma unroll
    for (int i = 0; i < 8; i++) { v[i] = row[t + i*256]; mx = fmaxf(mx, v[i]); }
    __shared__ float red[6];
    int w = t >> 6, lane = t & 63;
    #pragma unroll
    for (int off = 32; off; off >>= 1) mx = fmaxf(mx, __shfl_down(mx, off));
    if (lane == 0) red[w] = mx;
    __syncthreads();
    if (t == 0) { float m2 = fmaxf(fmaxf(red[0],red[1]), fmaxf(red[2],red[3])); red[4] = m2; }
    __syncthreads();
    mx = red[4];
    float sum = 0.f;
    #pragma unroll
    for (int i = 0; i < 8; i++) { v[i] = __expf(v[i] - mx); sum += v[i]; }
    #pragma unroll
    for (int off = 32; off; off >>= 1) sum += __shfl_down(sum, off);
    if (lane == 0) red[w] = sum;
    __syncthreads();
    if (t == 0) { red[5] = 1.f / (red[0]+red[1]+red[2]+red[3]); }
    __syncthreads();
    float rs = red[5];
    #pragma unroll
    for (int i = 0; i < 8; i++) attn[(size_t)b*MM + t + i*256] = v[i]*rs;
}

// ---------------- vocab logits: 50000x32x256 GEMM, 4v x 4b register tile ----------------
__global__ __launch_bounds__(256) void logits_kernel(
    const float* __restrict__ h,      // [B][G]
    const float* __restrict__ o1,     // [B][E]
    const float* __restrict__ Wv,     // [V][256]
    const float* __restrict__ bv,     // [V]
    float* __restrict__ logits)       // [B][V]
{
    __shared__ float Ut[256][32];
    __shared__ float Wt[32][132];
    int t = threadIdx.x;
    for (int i = t; i < 256*32; i += 256) {
        int e = i >> 5, b = i & 31;
        Ut[e][b] = (e < GG) ? h[b*GG + e] : o1[b*EE + (e - GG)];
    }
    int vg = t & 31;
    int bg = t >> 5;
    int v0 = blockIdx.x * 128;
    float acc[4][4];
    #pragma unroll
    for (int i = 0; i < 4; i++)
        #pragma unroll
        for (int j = 0; j < 4; j++) acc[i][j] = 0.f;

    int vrow = t >> 1;
    int half = t & 1;
    const float* wrow = Wv + (size_t)(v0 + vrow)*256 + half*16;
    bool vok = (v0 + vrow) < VV;

    for (int ec = 0; ec < 256; ec += 32) {
        __syncthreads();
        #pragma unroll
        for (int j = 0; j < 4; j++) {
            float4 w = make_float4(0.f, 0.f, 0.f, 0.f);
            if (vok) w = *(const float4*)(wrow + ec + j*4);
            int e0 = half*16 + j*4;
            Wt[e0+0][vrow] = w.x;
            Wt[e0+1][vrow] = w.y;
            Wt[e0+2][vrow] = w.z;
            Wt[e0+3][vrow] = w.w;
        }
        __syncthreads();
        #pragma unroll 8
        for (int e = 0; e < 32; e++) {
            float4 w = *(const float4*)(&Wt[e][vg*4]);
            float4 u = *(const float4*)(&Ut[ec + e][bg*4]);
            acc[0][0] += w.x*u.x; acc[0][1] += w.x*u.y; acc[0][2] += w.x*u.z; acc[0][3] += w.x*u.w;
            acc[1][0] += w.y*u.x; acc[1][1] += w.y*u.y; acc[1][2] += w.y*u.z; acc[1][3] += w.y*u.w;
            acc[2][0] += w.z*u.x; acc[2][1] += w.z*u.y; acc[2][2] += w.z*u.z; acc[2][3] += w.z*u.w;
            acc[3][0] += w.w*u.x; acc[3][1] += w.w*u.y; acc[3][2] += w.w*u.z; acc[3][3] += w.w*u.w;
        }
    }
    #pragma unroll
    for (int i = 0; i < 4; i++) {
        int v = v0 + vg*4 + i;
        if (v < VV) {
            float bb = bv[v];
            #pragma unroll
            for (int j = 0; j < 4; j++)
                logits[(size_t)(bg*4 + j)*VV + v] = acc[i][j] + bb;
        }
    }
}

// ---------------- vocab softmax partial stats: 8 chunks per batch row ----------------
#define VCHUNK 6250
__global__ __launch_bounds__(256) void vpart_kernel(
    const float* __restrict__ logits, // [B][V]
    float* __restrict__ part)         // [B][8][2] = {max, sumexp}
{
    int blk = blockIdx.x;             // b*8 + c
    int b = blk >> 3, c = blk & 7;
    int t = threadIdx.x;
    const float* row = logits + (size_t)b*VV;
    int start = c*VCHUNK;
    int end   = min(start + VCHUNK, VV);
    __shared__ float red[4];
    int w = t >> 6, lane = t & 63;
    float mx = -INFINITY;
    for (int i = start + t; i < end; i += 256) mx = fmaxf(mx, row[i]);
    #pragma unroll
    for (int off = 32; off; off >>= 1) mx = fmaxf(mx, __shfl_down(mx, off));
    if (lane == 0) red[w] = mx;
    __syncthreads();
    float m = fmaxf(fmaxf(red[0], red[1]), fmaxf(red[2], red[3]));
    float sum = 0.f;
    for (int i = start + t; i < end; i += 256) sum += __expf(row[i] - m);
    #pragma unroll
    for (int off = 32; off; off >>= 1) sum += __shfl_down(sum, off);
    __syncthreads();
    if (lane == 0) red[w] = sum;
    __syncthreads();
    if (t == 0) {
        part[blk*2]   = m;
        part[blk*2+1] = red[0] + red[1] + red[2] + red[3];
    }
}

// ---------------- finalize p_vocab in place ----------------
__global__ __launch_bounds__(256) void vfinal_kernel(
    float* __restrict__ logits,       // [B][V], in-place
    const float* __restrict__ part)   // [B][8][2]
{
    int i = blockIdx.x*256 + threadIdx.x;
    if (i >= BB*VV) return;
    int b = i / VV;
    const float* pp = part + b*16;
    float M = -INFINITY;
    #pragma unroll
    for (int c = 0; c < 8; c++) M = fmaxf(M, pp[c*2]);
    float S = 0.f;
    #pragma unroll
    for (int c = 0; c < 8; c++) S += pp[c*2+1] * __expf(pp[c*2] - M);
    logits[i] = __expf(logits[i] - M) * (1.f / S);
}

extern "C" void kernel_launch(void* const* d_in, const int* in_sizes, int n_in,
                              void* d_out, int out_size, void* d_ws, size_t ws_size,
                              hipStream_t stream) {
    const int*   ctx    = (const int*)  d_in[0];
    const float* h_prev = (const float*)d_in[1];
    const int*   y      = (const int*)  d_in[2];
    const float* emb    = (const float*)d_in[3];
    const float* W_ih   = (const float*)d_in[4];
    const float* W_hh   = (const float*)d_in[5];
    const float* b_ih   = (const float*)d_in[6];
    const float* b_hh   = (const float*)d_in[7];
    const float* Wv     = (const float*)d_in[8];
    const float* bv     = (const float*)d_in[9];

    float* out_h    = (float*)d_out;                 // [B][G]
    float* out_pv   = out_h + BB*GG;                 // [B][V]
    float* out_attn = out_pv + (size_t)BB*VV;        // [B][M]

    float* ws   = (float*)d_ws;
    float* q    = ws;                       // 4096
    float* o1   = q + BB*EE;                // 4096
    float* p    = o1 + BB*EE;               // 65536
    float* tbuf = p + BB*MM;                // B*V (6.4 MB)
    float* S1   = tbuf + (size_t)BB*VV;     // 33.5 MB
    float* S2   = S1 + (size_t)BB*MM*EE;    // 33.5 MB
    float* part = S2 + (size_t)BB*MM*EE;    // 512

    const float* e0 = emb;
    const float* e1 = emb + (size_t)1*VV*EE;
    const float* e2 = emb + (size_t)2*VV*EE;

    // GRU -> h, q ; zero o1
    gru_kernel<<<BB, 384, 0, stream>>>(emb, y, h_prev, W_ih, W_hh, b_ih, b_hh, out_h, q, o1);

    // hop 0: scores via table-0 stream + L2 lookup (t-trick); gather table1 + write S1
    t_kernel<<<391, 256, 0, stream>>>(q, e0, tbuf);
    scores_lookup_kernel<<<(BB*MM)/256, 256, 0, stream>>>(tbuf, ctx, p);
    oacc_fused_kernel<1><<<BB*32, 256, 0, stream>>>(e1, ctx, p, S1, q, o1);

    // hop 1: streamed scores from S1; gather table2 + write S2
    scores_s_kernel<<<(BB*MM)/4, 256, 0, stream>>>(S1, q, p);
    oacc_fused_kernel<0><<<BB*32, 256, 0, stream>>>(e2, ctx, p, S2, q, nullptr);

    // hop 2: streamed scores from S2 + chipwide softmax -> attn (o/q dead in reference)
    scores_s_kernel<<<(BB*MM)/4, 256, 0, stream>>>(S2, q, p);
    softmax_m_kernel<<<BB, 256, 0, stream>>>(p, out_attn);

    // vocab head
    logits_kernel<<<391, 256, 0, stream>>>(out_h, o1, Wv, bv, out_pv);
    vpart_kernel<<<BB*8, 256, 0, stream>>>(out_pv, part);
    vfinal_kernel<<<(BB*VV + 255)/256, 256, 0, stream>>>(out_pv, part);
}

// Round 9
// 316.749 us; speedup vs baseline: 3.3023x; 1.0114x over previous
//
#include <hip/hip_runtime.h>
#include <math.h>

#define BB 32
#define MM 2048
#define KK 4
#define EE 128
#define GG 128
#define VV 50000
#define NT 391   // 128-row tiles over V

// ---------------- GRU cell: one block per batch row; also zeroes o1 ----------------
__global__ __launch_bounds__(384) void gru_kernel(
    const float* __restrict__ emb0,   // emb table 0 [V][E]
    const int*   __restrict__ y,      // [B]
    const float* __restrict__ hprev,  // [B][G]
    const float* __restrict__ W_ih,   // [3G][E]
    const float* __restrict__ W_hh,   // [3G][G]
    const float* __restrict__ b_ih,   // [3G]
    const float* __restrict__ b_hh,   // [3G]
    float* __restrict__ h_out,        // d_out [B][G]
    float* __restrict__ q,            // ws    [B][G]
    float* __restrict__ o1)           // ws    [B][E] -> zeroed (atomics later)
{
    int b = blockIdx.x;
    int t = threadIdx.x;
    __shared__ float x[EE], h[GG], gi[3*GG], gh[3*GG];
    if (t < EE)            x[t]       = emb0[(size_t)y[b]*EE + t];
    else if (t < 2*EE)     h[t-EE]    = hprev[b*GG + (t-EE)];
    if (t < EE) o1[b*EE + t] = 0.f;
    __syncthreads();
    {
        float accI = b_ih[t], accH = b_hh[t];
        const float* wi = W_ih + (size_t)t*EE;
        const float* wh = W_hh + (size_t)t*GG;
        #pragma unroll 8
        for (int e = 0; e < EE; e++) { accI += x[e]*wi[e]; accH += h[e]*wh[e]; }
        gi[t] = accI; gh[t] = accH;
    }
    __syncthreads();
    if (t < GG) {
        float r = 1.f/(1.f + __expf(-(gi[t]        + gh[t])));
        float z = 1.f/(1.f + __expf(-(gi[GG+t]     + gh[GG+t])));
        float n = tanhf(gi[2*GG+t] + r*gh[2*GG+t]);
        float hn = (1.f - z)*n + z*h[t];
        h_out[b*GG + t] = hn;
        q[b*GG + t]     = hn;
    }
}

// ---------------- t[b][v] = emb0[v] . q[b] : dense streaming GEMM (hop 0 scores) ----
__global__ __launch_bounds__(256) void t_kernel(
    const float* __restrict__ q,      // [B][E]
    const float* __restrict__ embT,   // [V][E]
    float* __restrict__ t)            // [B][V]
{
    __shared__ float Ut[EE][32];      // q transposed [e][b]
    __shared__ float Wt[32][132];     // [e_local][v_local], pad 128->132
    int tid = threadIdx.x;
    for (int i = tid; i < EE*32; i += 256) {
        int e = i >> 5, b = i & 31;
        Ut[e][b] = q[b*EE + e];
    }
    int vg = tid & 31;
    int bg = tid >> 5;
    int v0 = blockIdx.x * 128;
    float acc[4][4];
    #pragma unroll
    for (int i = 0; i < 4; i++)
        #pragma unroll
        for (int j = 0; j < 4; j++) acc[i][j] = 0.f;

    int vrow = tid >> 1;
    int half = tid & 1;
    const float* wrow = embT + (size_t)(v0 + vrow)*EE + half*16;
    bool vok = (v0 + vrow) < VV;

    for (int ec = 0; ec < EE; ec += 32) {
        __syncthreads();
        #pragma unroll
        for (int j = 0; j < 4; j++) {
            float4 w = make_float4(0.f, 0.f, 0.f, 0.f);
            if (vok) w = *(const float4*)(wrow + ec + j*4);
            int e0 = half*16 + j*4;
            Wt[e0+0][vrow] = w.x;
            Wt[e0+1][vrow] = w.y;
            Wt[e0+2][vrow] = w.z;
            Wt[e0+3][vrow] = w.w;
        }
        __syncthreads();
        #pragma unroll 8
        for (int e = 0; e < 32; e++) {
            float4 w = *(const float4*)(&Wt[e][vg*4]);
            float4 u = *(const float4*)(&Ut[ec + e][bg*4]);
            acc[0][0] += w.x*u.x; acc[0][1] += w.x*u.y; acc[0][2] += w.x*u.z; acc[0][3] += w.x*u.w;
            acc[1][0] += w.y*u.x; acc[1][1] += w.y*u.y; acc[1][2] += w.y*u.z; acc[1][3] += w.y*u.w;
            acc[2][0] += w.z*u.x; acc[2][1] += w.z*u.y; acc[2][2] += w.z*u.z; acc[2][3] += w.z*u.w;
            acc[3][0] += w.w*u.x; acc[3][1] += w.w*u.y; acc[3][2] += w.w*u.z; acc[3][3] += w.w*u.w;
        }
    }
    #pragma unroll
    for (int i = 0; i < 4; i++) {
        int v = v0 + vg*4 + i;
        if (v < VV) {
            #pragma unroll
            for (int j = 0; j < 4; j++)
                t[(size_t)(bg*4 + j)*VV + v] = acc[i][j];
        }
    }
}

// ---------------- hop 0 scores via t-lookup: p[b][m] = sum_k t[b][ctx] ----------------
__global__ __launch_bounds__(256) void scores_lookup_kernel(
    const float* __restrict__ t,      // [B][V]
    const int*   __restrict__ ctx,    // [B][M][K]
    float* __restrict__ p)            // [B][M]
{
    int gid = blockIdx.x*256 + threadIdx.x;   // == b*M + m
    int b   = gid >> 11;
    const int4 c = *(const int4*)(ctx + (size_t)gid*KK);
    const float* tb = t + (size_t)b*VV;
    p[gid] = tb[c.x] + tb[c.y] + tb[c.z] + tb[c.w];
}

// ---------------- fused: softmax stats + weighted gather + S write + q update ----------
// R1-proven. One block per (b, slot-chunk-of-64). Recomputes row softmax stats from p
// (8 KB read), gathers the C-table rows (unroll 4 -> 16 outstanding 512B row loads),
// writes S row-sums (weight tying: C of hop h == A of hop h+1), atomic-accumulates q/o1.
template<int SAVE_O1>
__global__ __launch_bounds__(256) void oacc_fused_kernel(
    const float* __restrict__ embT,   // emb + (hop+1)*V*E
    const int*   __restrict__ ctx,    // [B][M][K]
    const float* __restrict__ p,      // [B][M] raw scores
    float* __restrict__ S_out,        // [B*M][E] row sums
    float* __restrict__ q,            // [B][E] atomic +=
    float* __restrict__ o1)           // [B][E] atomic += (if SAVE_O1)
{
    int blk = blockIdx.x;             // b*32 + s
    int b = blk >> 5, s = blk & 31;
    int t = threadIdx.x;
    int w = t >> 6, lane = t & 63;

    const float* row = p + (size_t)b*MM;
    float v[8];
    float mx = -INFINITY;
    #pragma unroll
    for (int i = 0; i < 8; i++) { v[i] = row[t + i*256]; mx = fmaxf(mx, v[i]); }
    __shared__ float red[6];
    #pragma unroll
    for (int off = 32; off; off >>= 1) mx = fmaxf(mx, __shfl_down(mx, off));
    if (lane == 0) red[w] = mx;
    __syncthreads();
    if (t == 0) red[4] = fmaxf(fmaxf(red[0],red[1]), fmaxf(red[2],red[3]));
    __syncthreads();
    mx = red[4];
    float sum = 0.f;
    #pragma unroll
    for (int i = 0; i < 8; i++) sum += __expf(v[i] - mx);
    #pragma unroll
    for (int off = 32; off; off >>= 1) sum += __shfl_down(sum, off);
    __syncthreads();
    if (lane == 0) red[w] = sum;
    __syncthreads();
    if (t == 0) red[5] = 1.f / (red[0]+red[1]+red[2]+red[3]);
    __syncthreads();
    float rs = red[5];

    int m0 = s*64 + w*16;
    float ax = 0.f, ay = 0.f;
    #pragma unroll 4
    for (int i = 0; i < 16; i++) {
        int m = m0 + i;
        float a = __expf(row[m] - mx) * rs;
        const int4 c = *(const int4*)(ctx + (size_t)(b*MM + m)*KK);
        float2 v0 = *(const float2*)(embT + (size_t)c.x*EE + lane*2);
        float2 v1 = *(const float2*)(embT + (size_t)c.y*EE + lane*2);
        float2 v2 = *(const float2*)(embT + (size_t)c.z*EE + lane*2);
        float2 v3 = *(const float2*)(embT + (size_t)c.w*EE + lane*2);
        float sx = v0.x + v1.x + v2.x + v3.x;
        float sy = v0.y + v1.y + v2.y + v3.y;
        *(float2*)(S_out + ((size_t)b*MM + m)*EE + lane*2) = make_float2(sx, sy);
        ax += a * sx;
        ay += a * sy;
    }
    __shared__ float acc_red[4][EE];
    acc_red[w][lane*2]   = ax;
    acc_red[w][lane*2+1] = ay;
    __syncthreads();
    if (t < EE) {
        float vv = acc_red[0][t] + acc_red[1][t] + acc_red[2][t] + acc_red[3][t];
        atomicAdd(&q[b*EE + t], vv);
        if (SAVE_O1) atomicAdd(&o1[b*EE + t], vv);
    }
}

// ---------------- streamed scores from S: p[b][m] = S[b][m].q[b] ----------------
__global__ __launch_bounds__(256) void scores_s_kernel(
    const float* __restrict__ S,      // [B*M][E]
    const float* __restrict__ q,      // [B][E]
    float* __restrict__ p)            // [B][M]
{
    int gid  = blockIdx.x * 4 + (threadIdx.x >> 6);
    int lane = threadIdx.x & 63;
    int b    = gid >> 11;
    float2 sv = *(const float2*)(S + (size_t)gid*EE + lane*2);
    float2 qv = *(const float2*)(q + b*EE + lane*2);
    float acc = sv.x*qv.x + sv.y*qv.y;
    #pragma unroll
    for (int off = 32; off; off >>= 1) acc += __shfl_down(acc, off);
    if (lane == 0) p[gid] = acc;
}

// ---------------- softmax over M: writes final attn output (hop 2) ----------------
__global__ __launch_bounds__(256) void softmax_m_kernel(
    const float* __restrict__ p,      // [B][M]
    float* __restrict__ attn)         // [B][M]
{
    int b = blockIdx.x, t = threadIdx.x;
    const float* row = p + (size_t)b*MM;
    float v[8];
    float mx = -INFINITY;
    #pragma unroll
    for (int i = 0; i < 8; i++) { v[i] = row[t + i*256]; mx = fmaxf(mx, v[i]); }
    __shared__ float red[6];
    int w = t >> 6, lane = t & 63;
    #pragma unroll
    for (int off = 32; off; off >>= 1) mx = fmaxf(mx, __shfl_down(mx, off));
    if (lane == 0) red[w] = mx;
    __syncthreads();
    if (t == 0) { float m2 = fmaxf(fmaxf(red[0],red[1]), fmaxf(red[2],red[3])); red[4] = m2; }
    __syncthreads();
    mx = red[4];
    float sum = 0.f;
    #pragma unroll
    for (int i = 0; i < 8; i++) { v[i] = __expf(v[i] - mx); sum += v[i]; }
    #pragma unroll
    for (int off = 32; off; off >>= 1) sum += __shfl_down(sum, off);
    if (lane == 0) red[w] = sum;
    __syncthreads();
    if (t == 0) { red[5] = 1.f / (red[0]+red[1]+red[2]+red[3]); }
    __syncthreads();
    float rs = red[5];
    #pragma unroll
    for (int i = 0; i < 8; i++) attn[(size_t)b*MM + t + i*256] = v[i]*rs;
}

// ---------------- vocab logits GEMM + per-tile vocab-softmax partials ----------------
// Epilogue addition: per (tile, b) {max, sumexp} partial via 32-lane shuffle reduce
// (the 32 vg-threads of a bg-group are contiguous -> width-32 shfl). Kills vpart.
__global__ __launch_bounds__(256) void logits_kernel(
    const float* __restrict__ h,      // [B][G]
    const float* __restrict__ o1,     // [B][E]
    const float* __restrict__ Wv,     // [V][256]
    const float* __restrict__ bv,     // [V]
    float* __restrict__ logits,       // [B][V]
    float* __restrict__ part)         // [B][NT][2] = {max, sumexp} per tile
{
    __shared__ float Ut[256][32];
    __shared__ float Wt[32][132];
    int t = threadIdx.x;
    for (int i = t; i < 256*32; i += 256) {
        int e = i >> 5, b = i & 31;
        Ut[e][b] = (e < GG) ? h[b*GG + e] : o1[b*EE + (e - GG)];
    }
    int vg = t & 31;
    int bg = t >> 5;
    int v0 = blockIdx.x * 128;
    float acc[4][4];
    #pragma unroll
    for (int i = 0; i < 4; i++)
        #pragma unroll
        for (int j = 0; j < 4; j++) acc[i][j] = 0.f;

    int vrow = t >> 1;
    int half = t & 1;
    const float* wrow = Wv + (size_t)(v0 + vrow)*256 + half*16;
    bool vrok = (v0 + vrow) < VV;

    for (int ec = 0; ec < 256; ec += 32) {
        __syncthreads();
        #pragma unroll
        for (int j = 0; j < 4; j++) {
            float4 w = make_float4(0.f, 0.f, 0.f, 0.f);
            if (vrok) w = *(const float4*)(wrow + ec + j*4);
            int e0 = half*16 + j*4;
            Wt[e0+0][vrow] = w.x;
            Wt[e0+1][vrow] = w.y;
            Wt[e0+2][vrow] = w.z;
            Wt[e0+3][vrow] = w.w;
        }
        __syncthreads();
        #pragma unroll 8
        for (int e = 0; e < 32; e++) {
            float4 w = *(const float4*)(&Wt[e][vg*4]);
            float4 u = *(const float4*)(&Ut[ec + e][bg*4]);
            acc[0][0] += w.x*u.x; acc[0][1] += w.x*u.y; acc[0][2] += w.x*u.z; acc[0][3] += w.x*u.w;
            acc[1][0] += w.y*u.x; acc[1][1] += w.y*u.y; acc[1][2] += w.y*u.z; acc[1][3] += w.y*u.w;
            acc[2][0] += w.z*u.x; acc[2][1] += w.z*u.y; acc[2][2] += w.z*u.z; acc[2][3] += w.z*u.w;
            acc[3][0] += w.w*u.x; acc[3][1] += w.w*u.y; acc[3][2] += w.w*u.z; acc[3][3] += w.w*u.w;
        }
    }
    // epilogue: write logits, keep values (with bias) for partial softmax stats
    #pragma unroll
    for (int i = 0; i < 4; i++) {
        int v = v0 + vg*4 + i;
        bool ok = v < VV;
        float bb = ok ? bv[v] : 0.f;
        #pragma unroll
        for (int j = 0; j < 4; j++) {
            float val = ok ? (acc[i][j] + bb) : -INFINITY;
            acc[i][j] = val;
            if (ok) logits[(size_t)(bg*4 + j)*VV + v] = val;
        }
    }
    // per-(tile,b) partial {max, sumexp}: reduce across the 32 vg-threads (width-32 shfl)
    #pragma unroll
    for (int j = 0; j < 4; j++) {
        float m = fmaxf(fmaxf(acc[0][j], acc[1][j]), fmaxf(acc[2][j], acc[3][j]));
        #pragma unroll
        for (int off = 16; off; off >>= 1) m = fmaxf(m, __shfl_down(m, off, 32));
        m = __shfl(m, 0, 32);
        float s = 0.f;
        #pragma unroll
        for (int i = 0; i < 4; i++) s += __expf(acc[i][j] - m);
        #pragma unroll
        for (int off = 16; off; off >>= 1) s += __shfl_down(s, off, 32);
        if (vg == 0) {
            int b = bg*4 + j;
            part[((size_t)b*NT + blockIdx.x)*2]     = m;
            part[((size_t)b*NT + blockIdx.x)*2 + 1] = s;
        }
    }
}

// ---------------- finalize p_vocab: block-cooperative combine of NT partials ----------
// Each 256-thread block covers 256 consecutive elements (at most 2 batch rows).
// Online {max,sum} merge of the 391 partials (L2-broadcast, ~3 KB/b) then normalize.
__global__ __launch_bounds__(256) void vfinal_kernel(
    float* __restrict__ logits,       // [B][V], in-place
    const float* __restrict__ part)   // [B][NT][2]
{
    int i0  = blockIdx.x*256;
    int tid = threadIdx.x;
    int b0  = i0 / VV;
    int last = min(i0 + 255, BB*VV - 1);
    int bL  = last / VV;
    __shared__ float redm[256], reds[256];
    __shared__ float statM[2], statR[2];
    for (int pass = 0; pass < 2; pass++) {
        int b = b0 + pass;
        if (b > bL) break;
        float m = -INFINITY, s = 0.f;
        for (int tt = tid; tt < NT; tt += 256) {
            float pm = part[((size_t)b*NT + tt)*2];
            float ps = part[((size_t)b*NT + tt)*2 + 1];
            float M2 = fmaxf(m, pm);
            s = s*__expf(m - M2) + ps*__expf(pm - M2);
            m = M2;
        }
        redm[tid] = m; reds[tid] = s;
        __syncthreads();
        for (int off = 128; off; off >>= 1) {
            if (tid < off) {
                float m2 = redm[tid+off], s2 = reds[tid+off];
                float M2 = fmaxf(redm[tid], m2);
                reds[tid] = reds[tid]*__expf(redm[tid]-M2) + s2*__expf(m2-M2);
                redm[tid] = M2;
            }
            __syncthreads();
        }
        if (tid == 0) { statM[pass] = redm[0]; statR[pass] = 1.f / reds[0]; }
        __syncthreads();
    }
    int i = i0 + tid;
    if (i < BB*VV) {
        int b = i / VV;
        int pass = b - b0;
        logits[i] = __expf(logits[i] - statM[pass]) * statR[pass];
    }
}

extern "C" void kernel_launch(void* const* d_in, const int* in_sizes, int n_in,
                              void* d_out, int out_size, void* d_ws, size_t ws_size,
                              hipStream_t stream) {
    const int*   ctx    = (const int*)  d_in[0];
    const float* h_prev = (const float*)d_in[1];
    const int*   y      = (const int*)  d_in[2];
    const float* emb    = (const float*)d_in[3];
    const float* W_ih   = (const float*)d_in[4];
    const float* W_hh   = (const float*)d_in[5];
    const float* b_ih   = (const float*)d_in[6];
    const float* b_hh   = (const float*)d_in[7];
    const float* Wv     = (const float*)d_in[8];
    const float* bv     = (const float*)d_in[9];

    float* out_h    = (float*)d_out;                 // [B][G]
    float* out_pv   = out_h + BB*GG;                 // [B][V]
    float* out_attn = out_pv + (size_t)BB*VV;        // [B][M]

    float* ws   = (float*)d_ws;
    float* q    = ws;                       // 4096
    float* o1   = q + BB*EE;                // 4096
    float* p    = o1 + BB*EE;               // 65536
    float* tbuf = p + BB*MM;                // B*V (6.4 MB)
    float* S1   = tbuf + (size_t)BB*VV;     // 33.5 MB
    float* S2   = S1 + (size_t)BB*MM*EE;    // 33.5 MB
    float* part = S2 + (size_t)BB*MM*EE;    // B*NT*2 = 25024 floats

    const float* e0 = emb;
    const float* e1 = emb + (size_t)1*VV*EE;
    const float* e2 = emb + (size_t)2*VV*EE;

    // GRU -> h, q ; zero o1
    gru_kernel<<<BB, 384, 0, stream>>>(emb, y, h_prev, W_ih, W_hh, b_ih, b_hh, out_h, q, o1);

    // hop 0: scores via table-0 stream + L2 lookup (t-trick); gather table1 + write S1
    t_kernel<<<NT, 256, 0, stream>>>(q, e0, tbuf);
    scores_lookup_kernel<<<(BB*MM)/256, 256, 0, stream>>>(tbuf, ctx, p);
    oacc_fused_kernel<1><<<BB*32, 256, 0, stream>>>(e1, ctx, p, S1, q, o1);

    // hop 1: streamed scores from S1; gather table2 + write S2
    scores_s_kernel<<<(BB*MM)/4, 256, 0, stream>>>(S1, q, p);
    oacc_fused_kernel<0><<<BB*32, 256, 0, stream>>>(e2, ctx, p, S2, q, nullptr);

    // hop 2: streamed scores from S2 + chipwide softmax -> attn (o/q dead in reference)
    scores_s_kernel<<<(BB*MM)/4, 256, 0, stream>>>(S2, q, p);
    softmax_m_kernel<<<BB, 256, 0, stream>>>(p, out_attn);

    // vocab head: logits GEMM emits softmax partials; vfinal combines + normalizes
    logits_kernel<<<NT, 256, 0, stream>>>(out_h, o1, Wv, bv, out_pv, part);
    vfinal_kernel<<<(BB*VV + 255)/256, 256, 0, stream>>>(out_pv, part);
}